// Round 2
// baseline (179.454 us; speedup 1.0000x reference)
//
#include <hip/hip_runtime.h>
#include <math.h>

#define HW    9216
#define KJ    17
#define BATCH 128
#define TOPK  8

// Kernel 1: per-(b,k) sum of squared diff. One block per row (b*17+k).
// 256 threads x 9 float4 per input = 9216 floats per row, fully coalesced.
// All 18 loads issued before any use -> 18 outstanding dwordx4 per thread
// (the previous version had VGPR=32 and a serialized 9-deep latency chain).
__global__ __launch_bounds__(256) void per_joint_mse(
    const float* __restrict__ outp, const float* __restrict__ tgt,
    const float* __restrict__ tw, float* __restrict__ pj)
{
    const int row = blockIdx.x;            // b*KJ + k
    const float4* o4 = (const float4*)(outp + (size_t)row * HW);
    const float4* t4 = (const float4*)(tgt  + (size_t)row * HW);
    const int tid = threadIdx.x;

    float4 o[9], t[9];
#pragma unroll
    for (int j = 0; j < 9; ++j) o[j] = o4[tid + j * 256];
#pragma unroll
    for (int j = 0; j < 9; ++j) t[j] = t4[tid + j * 256];

    float acc = 0.f;
#pragma unroll
    for (int j = 0; j < 9; ++j) {
        float d0 = o[j].x - t[j].x;
        float d1 = o[j].y - t[j].y;
        float d2 = o[j].z - t[j].z;
        float d3 = o[j].w - t[j].w;
        acc += d0 * d0 + d1 * d1 + d2 * d2 + d3 * d3;
    }

    // wave64 shuffle reduce
#pragma unroll
    for (int off = 32; off > 0; off >>= 1)
        acc += __shfl_down(acc, off, 64);

    __shared__ float smem[4];
    const int wave = tid >> 6;
    if ((tid & 63) == 0) smem[wave] = acc;
    __syncthreads();
    if (tid == 0) {
        const float w = tw[row];
        float tot = smem[0] + smem[1] + smem[2] + smem[3];
        pj[row] = tot * w * w * (1.0f / (float)HW);
    }
}

// Kernel 2: per-sample top-8-of-17, then mean over batch. 1 block, 128 threads.
__global__ __launch_bounds__(128) void ohkm_reduce(
    const float* __restrict__ pj, float* __restrict__ result)
{
    const int b = threadIdx.x;   // 0..127 — one sample per thread
    float v[KJ];
#pragma unroll
    for (int k = 0; k < KJ; ++k) v[k] = pj[b * KJ + k];

    float s = 0.f;
#pragma unroll
    for (int t = 0; t < TOPK; ++t) {
        float m = v[0];
#pragma unroll
        for (int k = 1; k < KJ; ++k) m = fmaxf(m, v[k]);
        s += m;
        // remove exactly the FIRST element equal to m (tie-safe top_k semantics)
        bool removed = false;
#pragma unroll
        for (int k = 0; k < KJ; ++k) {
            bool hit = (!removed) && (v[k] == m);
            v[k] = hit ? -INFINITY : v[k];
            removed = removed || hit;
        }
    }

    // 128 threads = 2 waves
#pragma unroll
    for (int off = 32; off > 0; off >>= 1)
        s += __shfl_down(s, off, 64);

    __shared__ float smem[2];
    if ((b & 63) == 0) smem[b >> 6] = s;
    __syncthreads();
    if (b == 0)
        result[0] = (smem[0] + smem[1]) * (1.0f / (float)(BATCH * TOPK));
}

extern "C" void kernel_launch(void* const* d_in, const int* in_sizes, int n_in,
                              void* d_out, int out_size, void* d_ws, size_t ws_size,
                              hipStream_t stream) {
    const float* outp = (const float*)d_in[0];   // [128,17,96,96]
    const float* tgt  = (const float*)d_in[1];   // [128,17,96,96]
    const float* tw   = (const float*)d_in[2];   // [128,17,1]
    float* result = (float*)d_out;               // scalar
    float* pj = (float*)d_ws;                    // [128*17] per-joint MSE

    per_joint_mse<<<BATCH * KJ, 256, 0, stream>>>(outp, tgt, tw, pj);
    ohkm_reduce<<<1, 128, 0, stream>>>(pj, result);
}

// Round 3
// 176.256 us; speedup vs baseline: 1.0181x; 1.0181x over previous
//
#include <hip/hip_runtime.h>
#include <math.h>

#define HW    9216
#define KJ    17
#define BATCH 128
#define TOPK  8

// Kernel 1: per-(b,k) sum of squared diff. One block per row (b*17+k).
// 256 threads x 9 float4 per input = 9216 floats per row, fully coalesced.
// sched_barrier(0) forces all 18 global_load_dwordx4 to issue before any
// compute: R1 showed the scheduler sinks them (VGPR=32, 60us latency-bound).
__global__ __launch_bounds__(256) void per_joint_mse(
    const float* __restrict__ outp, const float* __restrict__ tgt,
    const float* __restrict__ tw, float* __restrict__ pj)
{
    const int row = blockIdx.x;            // b*KJ + k
    const float4* o4 = (const float4*)(outp + (size_t)row * HW);
    const float4* t4 = (const float4*)(tgt  + (size_t)row * HW);
    const int tid = threadIdx.x;

    float4 o[9], t[9];
#pragma unroll
    for (int j = 0; j < 9; ++j) {
        o[j] = o4[tid + j * 256];
        t[j] = t4[tid + j * 256];
    }
    // Nothing crosses this: all 18 loads must be in flight before compute.
    __builtin_amdgcn_sched_barrier(0);

    float acc = 0.f;
#pragma unroll
    for (int j = 0; j < 9; ++j) {
        float d0 = o[j].x - t[j].x;
        float d1 = o[j].y - t[j].y;
        float d2 = o[j].z - t[j].z;
        float d3 = o[j].w - t[j].w;
        acc += d0 * d0 + d1 * d1 + d2 * d2 + d3 * d3;
    }

    // wave64 shuffle reduce
#pragma unroll
    for (int off = 32; off > 0; off >>= 1)
        acc += __shfl_down(acc, off, 64);

    __shared__ float smem[4];
    const int wave = tid >> 6;
    if ((tid & 63) == 0) smem[wave] = acc;
    __syncthreads();
    if (tid == 0) {
        const float w = tw[row];
        float tot = smem[0] + smem[1] + smem[2] + smem[3];
        pj[row] = tot * w * w * (1.0f / (float)HW);
    }
}

// Kernel 2: per-sample top-8-of-17, then mean over batch. 1 block, 128 threads.
__global__ __launch_bounds__(128) void ohkm_reduce(
    const float* __restrict__ pj, float* __restrict__ result)
{
    const int b = threadIdx.x;   // 0..127 — one sample per thread
    float v[KJ];
#pragma unroll
    for (int k = 0; k < KJ; ++k) v[k] = pj[b * KJ + k];

    float s = 0.f;
#pragma unroll
    for (int t = 0; t < TOPK; ++t) {
        float m = v[0];
#pragma unroll
        for (int k = 1; k < KJ; ++k) m = fmaxf(m, v[k]);
        s += m;
        // remove exactly the FIRST element equal to m (tie-safe top_k semantics)
        bool removed = false;
#pragma unroll
        for (int k = 0; k < KJ; ++k) {
            bool hit = (!removed) && (v[k] == m);
            v[k] = hit ? -INFINITY : v[k];
            removed = removed || hit;
        }
    }

    // 128 threads = 2 waves
#pragma unroll
    for (int off = 32; off > 0; off >>= 1)
        s += __shfl_down(s, off, 64);

    __shared__ float smem[2];
    if ((b & 63) == 0) smem[b >> 6] = s;
    __syncthreads();
    if (b == 0)
        result[0] = (smem[0] + smem[1]) * (1.0f / (float)(BATCH * TOPK));
}

extern "C" void kernel_launch(void* const* d_in, const int* in_sizes, int n_in,
                              void* d_out, int out_size, void* d_ws, size_t ws_size,
                              hipStream_t stream) {
    const float* outp = (const float*)d_in[0];   // [128,17,96,96]
    const float* tgt  = (const float*)d_in[1];   // [128,17,96,96]
    const float* tw   = (const float*)d_in[2];   // [128,17,1]
    float* result = (float*)d_out;               // scalar
    float* pj = (float*)d_ws;                    // [128*17] per-joint MSE

    per_joint_mse<<<BATCH * KJ, 256, 0, stream>>>(outp, tgt, tw, pj);
    ohkm_reduce<<<1, 128, 0, stream>>>(pj, result);
}